// Round 20
// baseline (29.846 us; speedup 1.0000x reference)
//
#include <hip/hip_runtime.h>
#include <hip/hip_bf16.h>
#include <hip/hip_cooperative_groups.h>
#include <cstddef>

#define B_ 8
#define C_ 2048
#define E_ 256
#define H_ 64
#define T_ 512
#define NA 4
#define KAPPA 0.9f
#define LOG2_KAPPA (-0.15200309344504997f)   // log2(0.9)
#define KAPPA_T 3.73302e-24f                 // 0.9^512

typedef __attribute__((ext_vector_type(8))) short bf16x8;
typedef __attribute__((ext_vector_type(4))) float f32x4;
typedef __attribute__((ext_vector_type(4))) unsigned u32x4;

__device__ inline unsigned short f2bfu(float x) {
    unsigned u = __builtin_bit_cast(unsigned, x);
    u += 0x7fff + ((u >> 16) & 1);   // RNE
    return (unsigned short)(u >> 16);
}
__device__ inline float bf2f(unsigned short u) {
    return __builtin_bit_cast(float, (unsigned)u << 16);
}
__device__ inline unsigned pack2bf(float lo, float hi) {
    return (unsigned)f2bfu(lo) | ((unsigned)f2bfu(hi) << 16);
}
// packed RNE cvt: lowers to v_cvt_pk_bf16_f32 (1 VALU op / 2 elems).
__device__ inline unsigned cvtpk(float a, float b) {
    __hip_bfloat162 h = __float22bfloat162_rn(float2{a, b});
    unsigned r;
    __builtin_memcpy(&r, &h, sizeof(r));
    return r;
}

// ---------------- shared device subroutines ---------------------------------
__device__ inline void do_proj_block(
    int bid, int t, const float* A, const float* Wg, unsigned short* O16,
    char* Wt)
{
    const int b    = bid & 7;
    const int rb   = (bid & 255) >> 3;
    const int row0 = b * C_ + rb * 64;
    const int lane = t & 63;
    const int lr   = lane & 15;
    const int lg   = lane >> 4;
    const int swz  = (lr & 7) << 4;

    // in-block W transpose: W[256][64] f32 -> swizzled bf16 Wt
#pragma unroll
    for (int p = 0; p < 8; ++p) {
        int idx = p * 256 + t;
        int kpair = idx >> 4;
        int dq    = (idx & 15) * 4;
        f32x4 r0 = *(const f32x4*)&Wg[(size_t)(2 * kpair)     * H_ + dq];
        f32x4 r1 = *(const f32x4*)&Wg[(size_t)(2 * kpair + 1) * H_ + dq];
#pragma unroll
        for (int j = 0; j < 4; ++j) {
            int d = dq + j;
            *(unsigned*)&Wt[(d << 9) + ((4 * kpair) ^ ((d & 7) << 4))] =
                cvtpk(r0[j], r1[j]);
        }
    }

    const float* arow = &A[(size_t)(row0 + (t >> 6) * 16 + lr) * E_ + lg * 8];
    f32x4 x0 = *(const f32x4*)(arow);
    f32x4 x1 = *(const f32x4*)(arow + 4);
    __syncthreads();

    f32x4 acc[4] = {};
#pragma unroll
    for (int kc = 0; kc < 8; ++kc) {
        f32x4 n0, n1;
        if (kc < 7) {
            n0 = *(const f32x4*)(arow + (kc + 1) * 32);
            n1 = *(const f32x4*)(arow + (kc + 1) * 32 + 4);
        }
        u32x4 afu = { cvtpk(x0[0], x0[1]), cvtpk(x0[2], x0[3]),
                      cvtpk(x1[0], x1[1]), cvtpk(x1[2], x1[3]) };
        bf16x8 af = __builtin_bit_cast(bf16x8, afu);
#pragma unroll
        for (int nt = 0; nt < 4; ++nt) {
            bf16x8 bfrag = *(const bf16x8*)&Wt[((nt * 16 + lr) << 9) +
                                               ((kc * 64 + lg * 16) ^ swz)];
            acc[nt] = __builtin_amdgcn_mfma_f32_16x16x32_bf16(af, bfrag, acc[nt], 0, 0, 0);
        }
        x0 = n0; x1 = n1;
    }

    const int odd   = lr & 1;
    const int rbase = row0 + (t >> 6) * 16 + lg * 4;
#pragma unroll
    for (int nt = 0; nt < 4; ++nt) {
        const int cp = nt * 16 + (lr & ~1);
        float x0_ = acc[nt][0], x1_ = acc[nt][1], x2_ = acc[nt][2], x3_ = acc[nt][3];
        float y0 = __shfl_xor(x0_, 1), y1 = __shfl_xor(x1_, 1);
        float y2 = __shfl_xor(x2_, 1), y3 = __shfl_xor(x3_, 1);
        if (!odd) {
            *(unsigned*)&O16[(size_t)(rbase + 0) * H_ + cp] = pack2bf(x0_, y0);
            *(unsigned*)&O16[(size_t)(rbase + 1) * H_ + cp] = pack2bf(x1_, y1);
        } else {
            *(unsigned*)&O16[(size_t)(rbase + 2) * H_ + cp] = pack2bf(y2, x2_);
            *(unsigned*)&O16[(size_t)(rbase + 3) * H_ + cp] = pack2bf(y3, x3_);
        }
    }
}

__device__ inline void do_stab_block(
    int b, int t, const unsigned char* raw, int* s_tab)
{
    const int lane = t & 63;
    const int wv   = t >> 6;
    __shared__ int f;
    __shared__ unsigned long long msk[8];
    if (t == 0) f = 0;
    __syncthreads();
    {   // layout detection: bool(1B) vs int32(4B LE 0/1)
        const uint4* dp = (const uint4*)raw;
        unsigned acc = 0;
#pragma unroll
        for (int i = 0; i < 4; ++i) {
            uint4 v = dp[t + 256 * i];     // 16KB = B_*C_ bytes
            acc |= (v.x | v.y | v.z | v.w) & 0xFFFFFF00u;
        }
        if (acc) f = 1;
    }
    __syncthreads();
    const int stride = f ? 1 : 4;
    const unsigned char* drow = raw + (size_t)b * C_ * stride;
#pragma unroll
    for (int cc = 0; cc < 2; ++cc) {
        const int c = 2 * wv + cc;
        const int n = c * 64 + lane;
        unsigned long long m = __ballot(drow[(size_t)(4 * n) * stride] != 0);
        if (lane == 0) msk[c] = m;
    }
    __syncthreads();
#pragma unroll
    for (int cc = 0; cc < 2; ++cc) {
        const int c = 2 * wv + cc;
        const int n = c * 64 + lane;
        unsigned long long lowmask =
            (lane == 63) ? ~0ULL : ((1ULL << (lane + 1)) - 1ULL);
        unsigned long long m_le = msk[c] & lowmask;
        int s = -1;
        if (m_le) {
            s = c * 64 + (63 - __builtin_clzll(m_le));
        } else {
            for (int c2 = c - 1; c2 >= 0; --c2)
                if (msk[c2]) { s = c2 * 64 + (63 - __builtin_clzll(msk[c2])); break; }
        }
        s_tab[b * T_ + n] = s;
    }
}

__device__ inline void do_out0_unit(
    int bid, int t, const unsigned short* qp, const unsigned short* kp,
    const unsigned short* vp, const float* hs, const int* s_tab, float* out0)
{
    const int lane = t & 63;
    const int wv   = t >> 6;
    const int b = bid & 7;
    const int n = (bid >> 3) * 4 + wv;
    const int a = lane >> 4;
    const int g = lane & 15;

    const int st = s_tab[b * T_ + n];
    const int s  = (st < 0) ? 0 : st;

    const unsigned short* kb = kp + (size_t)b * C_ * H_;
    const unsigned short* vb = vp + (size_t)b * C_ * H_;
    ushort4 qu = *(const ushort4*)&qp[((size_t)b * C_ + 4 * n + a) * H_ + 4 * g];
    f32x4 q4 = { bf2f(qu.x), bf2f(qu.y), bf2f(qu.z), bf2f(qu.w) };

    f32x4 acc = {};
#pragma unroll
    for (int ma = 0; ma < NA; ++ma) {
        const int m = 4 * n + ma;
        ushort4 ku = *(const ushort4*)&kb[(size_t)m * H_ + 4 * g];
        float p = q4[0] * bf2f(ku.x) + q4[1] * bf2f(ku.y)
                + q4[2] * bf2f(ku.z) + q4[3] * bf2f(ku.w);
        p += __shfl_xor(p, 1); p += __shfl_xor(p, 2);
        p += __shfl_xor(p, 4); p += __shfl_xor(p, 8);
        if (ma <= a) {
            ushort4 vu = *(const ushort4*)&vb[(size_t)m * H_ + 4 * g];
            acc[0] += p * bf2f(vu.x); acc[1] += p * bf2f(vu.y);
            acc[2] += p * bf2f(vu.z); acc[3] += p * bf2f(vu.w);
        }
    }
    float decay = KAPPA;
    for (int mt = n - 1; mt >= s; --mt) {
#pragma unroll
        for (int ma = 0; ma < NA; ++ma) {
            const int m = 4 * mt + ma;
            ushort4 ku = *(const ushort4*)&kb[(size_t)m * H_ + 4 * g];
            float p = q4[0] * bf2f(ku.x) + q4[1] * bf2f(ku.y)
                    + q4[2] * bf2f(ku.z) + q4[3] * bf2f(ku.w);
            p += __shfl_xor(p, 1); p += __shfl_xor(p, 2);
            p += __shfl_xor(p, 4); p += __shfl_xor(p, 8);
            p *= decay;
            ushort4 vu = *(const ushort4*)&vb[(size_t)m * H_ + 4 * g];
            acc[0] += p * bf2f(vu.x); acc[1] += p * bf2f(vu.y);
            acc[2] += p * bf2f(vu.z); acc[3] += p * bf2f(vu.w);
        }
        decay *= KAPPA;
    }
    if (st < 0) {
        const float xi = exp2f(LOG2_KAPPA * (float)(n + 1));
        const float* hsb = hs + (size_t)b * H_ * H_;
        f32x4 cacc = {};
#pragma unroll
        for (int h = 0; h < H_; ++h) {
            float qh = __shfl(q4[h & 3], (a << 4) + (h >> 2));
            f32x4 h4 = *(const f32x4*)&hsb[h * H_ + 4 * g];
            cacc[0] += qh * h4[0]; cacc[1] += qh * h4[1];
            cacc[2] += qh * h4[2]; cacc[3] += qh * h4[3];
        }
        acc[0] += xi * cacc[0]; acc[1] += xi * cacc[1];
        acc[2] += xi * cacc[2]; acc[3] += xi * cacc[3];
    }
    *(f32x4*)&out0[((size_t)b * C_ + 4 * n + a) * H_ + 4 * g] = acc;
}

__device__ inline void do_nexth_unit(
    int j, int t, const unsigned short* kp, const unsigned short* vp,
    const float* hs, const int* s_tab, float* outh)
{
    const int lane = t & 63;
    const int wv   = t >> 6;
    const int b = j & 7;
    const int h = (j >> 3) * 4 + wv;
    const int d = lane;

    const int st = s_tab[b * T_ + (T_ - 1)];
    const int s  = (st < 0) ? 0 : st;

    const unsigned short* kb = kp + (size_t)b * C_ * H_;
    const unsigned short* vb = vp + (size_t)b * C_ * H_;
    float acc = 0.f, wdec = 1.f;
    for (int mt = T_ - 1; mt >= s; --mt) {
#pragma unroll
        for (int ma = 0; ma < NA; ++ma) {
            const int m = 4 * mt + ma;
            acc += wdec * bf2f(kb[(size_t)m * H_ + h]) *
                          bf2f(vb[(size_t)m * H_ + d]);
        }
        wdec *= KAPPA;
    }
    if (st < 0)
        acc += hs[((size_t)b * H_ + h) * H_ + d] * KAPPA_T;
    outh[((size_t)b * H_ + h) * H_ + d] = acc;
}

// ================== Path A: single cooperative kernel, 1024 blocks ==========
__global__ __launch_bounds__(256, 4) void fused_kernel(
    const float* __restrict__ key_in, const float* __restrict__ query,
    const float* __restrict__ value, const float* __restrict__ hs,
    const float* __restrict__ w_q, const float* __restrict__ w_k,
    const float* __restrict__ w_v,
    const unsigned char* __restrict__ raw,
    unsigned short* __restrict__ qp, unsigned short* __restrict__ kp,
    unsigned short* __restrict__ vp, int* __restrict__ s_tab,
    float* __restrict__ out0, float* __restrict__ outh)
{
    __shared__ __align__(16) char Wt[64 * 512];   // 32KB swizzled bf16 image
    const int t   = threadIdx.x;
    const int bid = blockIdx.x;

    if (bid < 768) {
        const int mat = bid >> 8;
        const float* A; unsigned short* O16; const float* Wg;
        if (mat == 0)      { A = query;  O16 = qp; Wg = w_q; }
        else if (mat == 1) { A = key_in; O16 = kp; Wg = w_k; }
        else               { A = value;  O16 = vp; Wg = w_v; }
        do_proj_block(bid, t, A, Wg, O16, Wt);
    } else if (bid < 776) {
        do_stab_block(bid - 768, t, raw, s_tab);
    }

    cooperative_groups::this_grid().sync();

    do_out0_unit(bid, t, qp, kp, vp, hs, s_tab, out0);
    if (bid >= 896)
        do_nexth_unit(bid - 896, t, kp, vp, hs, s_tab, outh);
}

// ================== Path B fallback: r18 two-kernel structure ===============
__global__ __launch_bounds__(256) void proj_kernelB(
    const float* __restrict__ key_in, const float* __restrict__ query,
    const float* __restrict__ value,
    const float* __restrict__ w_q, const float* __restrict__ w_k,
    const float* __restrict__ w_v,
    const unsigned char* __restrict__ raw,
    unsigned short* __restrict__ qp, unsigned short* __restrict__ kp,
    unsigned short* __restrict__ vp, int* __restrict__ s_tab)
{
    __shared__ __align__(16) char Wt[64 * 512];
    const int t   = threadIdx.x;
    const int bid = blockIdx.x;
    if (bid >= 768) { do_stab_block(bid - 768, t, raw, s_tab); return; }
    const int mat = bid >> 8;
    const float* A; unsigned short* O16; const float* Wg;
    if (mat == 0)      { A = query;  O16 = qp; Wg = w_q; }
    else if (mat == 1) { A = key_in; O16 = kp; Wg = w_k; }
    else               { A = value;  O16 = vp; Wg = w_v; }
    do_proj_block(bid, t, A, Wg, O16, Wt);
}

__global__ __launch_bounds__(256) void out_kernelB(
    const unsigned short* __restrict__ qp, const unsigned short* __restrict__ kp,
    const unsigned short* __restrict__ vp, const float* __restrict__ hs,
    const int* __restrict__ s_tab,
    float* __restrict__ out0, float* __restrict__ outh)
{
    const int t   = threadIdx.x;
    const int bid = blockIdx.x;
    if (bid < 1024) do_out0_unit(bid, t, qp, kp, vp, hs, s_tab, out0);
    else            do_nexth_unit(bid - 1024, t, kp, vp, hs, s_tab, outh);
}

extern "C" void kernel_launch(void* const* d_in, const int* in_sizes, int n_in,
                              void* d_out, int out_size, void* d_ws, size_t ws_size,
                              hipStream_t stream)
{
    const float* key_in = (const float*)d_in[0];
    const float* query  = (const float*)d_in[1];
    const float* value  = (const float*)d_in[2];
    const float* hstate = (const float*)d_in[3];
    const unsigned char* dones = (const unsigned char*)d_in[4];
    const float* w_q = (const float*)d_in[5];
    const float* w_k = (const float*)d_in[6];
    const float* w_v = (const float*)d_in[7];

    unsigned short* qp = (unsigned short*)d_ws;
    unsigned short* kp = qp + (size_t)B_ * C_ * H_;
    unsigned short* vp = kp + (size_t)B_ * C_ * H_;
    int*         s_tab = (int*)(vp + (size_t)B_ * C_ * H_);
    float*        out0 = (float*)d_out;
    float*        outh = (float*)d_out + (size_t)B_ * C_ * H_;

    // Host-side co-residency pre-check (pure query, graph-capture safe):
    int blocksPerCU = 0;
    hipError_t qerr = hipOccupancyMaxActiveBlocksPerMultiprocessor(
        &blocksPerCU, (const void*)fused_kernel, 256, 0);
    const bool coop_ok = (qerr == hipSuccess) && (blocksPerCU * 256 >= 1024);

    if (coop_ok) {
        void* args[] = {
            (void*)&key_in, (void*)&query, (void*)&value, (void*)&hstate,
            (void*)&w_q, (void*)&w_k, (void*)&w_v, (void*)&dones,
            (void*)&qp, (void*)&kp, (void*)&vp, (void*)&s_tab,
            (void*)&out0, (void*)&outh
        };
        hipLaunchCooperativeKernel((void*)fused_kernel, dim3(1024), dim3(256),
                                   args, 0, stream);
    } else {
        proj_kernelB<<<776, 256, 0, stream>>>(key_in, query, value,
                                              w_q, w_k, w_v, dones,
                                              qp, kp, vp, s_tab);
        out_kernelB<<<1024 + 128, 256, 0, stream>>>(qp, kp, vp, hstate, s_tab,
                                                    out0, outh);
    }
}

// Round 21
// 26.874 us; speedup vs baseline: 1.1106x; 1.1106x over previous
//
#include <hip/hip_runtime.h>
#include <hip/hip_bf16.h>
#include <cstddef>

#define B_ 8
#define C_ 2048
#define E_ 256
#define H_ 64
#define T_ 512
#define NA 4
#define KAPPA 0.9f
#define LOG2_KAPPA (-0.15200309344504997f)   // log2(0.9)
#define KAPPA_T 3.73302e-24f                 // 0.9^512

typedef __attribute__((ext_vector_type(8))) short bf16x8;
typedef __attribute__((ext_vector_type(4))) float f32x4;
typedef __attribute__((ext_vector_type(4))) unsigned u32x4;

__device__ inline unsigned short f2bfu(float x) {
    unsigned u = __builtin_bit_cast(unsigned, x);
    u += 0x7fff + ((u >> 16) & 1);   // RNE
    return (unsigned short)(u >> 16);
}
__device__ inline float bf2f(unsigned short u) {
    return __builtin_bit_cast(float, (unsigned)u << 16);
}
__device__ inline unsigned pack2bf(float lo, float hi) {
    return (unsigned)f2bfu(lo) | ((unsigned)f2bfu(hi) << 16);
}
// packed RNE cvt: lowers to v_cvt_pk_bf16_f32 (1 VALU op / 2 elems).
__device__ inline unsigned cvtpk(float a, float b) {
    __hip_bfloat162 h = __float22bfloat162_rn(float2{a, b});
    unsigned r;
    __builtin_memcpy(&r, &h, sizeof(r));
    return r;
}

// ---------------- shared device subroutines ---------------------------------
__device__ inline void do_stab_block(
    int b, int t, const unsigned char* raw, int* s_tab)
{
    const int lane = t & 63;
    const int wv   = t >> 6;
    __shared__ int f;
    __shared__ unsigned long long msk[8];
    if (t == 0) f = 0;
    __syncthreads();
    {   // layout detection: bool(1B) vs int32(4B LE 0/1)
        const uint4* dp = (const uint4*)raw;
        unsigned acc = 0;
#pragma unroll
        for (int i = 0; i < 4; ++i) {
            uint4 v = dp[t + 256 * i];     // 16KB = B_*C_ bytes
            acc |= (v.x | v.y | v.z | v.w) & 0xFFFFFF00u;
        }
        if (acc) f = 1;
    }
    __syncthreads();
    const int stride = f ? 1 : 4;
    const unsigned char* drow = raw + (size_t)b * C_ * stride;
#pragma unroll
    for (int cc = 0; cc < 2; ++cc) {
        const int c = 2 * wv + cc;
        const int n = c * 64 + lane;
        unsigned long long m = __ballot(drow[(size_t)(4 * n) * stride] != 0);
        if (lane == 0) msk[c] = m;
    }
    __syncthreads();
#pragma unroll
    for (int cc = 0; cc < 2; ++cc) {
        const int c = 2 * wv + cc;
        const int n = c * 64 + lane;
        unsigned long long lowmask =
            (lane == 63) ? ~0ULL : ((1ULL << (lane + 1)) - 1ULL);
        unsigned long long m_le = msk[c] & lowmask;
        int s = -1;
        if (m_le) {
            s = c * 64 + (63 - __builtin_clzll(m_le));
        } else {
            for (int c2 = c - 1; c2 >= 0; --c2)
                if (msk[c2]) { s = c2 * 64 + (63 - __builtin_clzll(msk[c2])); break; }
        }
        s_tab[b * T_ + n] = s;
    }
}

__device__ inline void do_out0_unit(
    int bid, int t, const unsigned short* qp, const unsigned short* kp,
    const unsigned short* vp, const float* hs, const int* s_tab, float* out0)
{
    const int lane = t & 63;
    const int wv   = t >> 6;
    const int b = bid & 7;
    const int n = (bid >> 3) * 4 + wv;
    const int a = lane >> 4;
    const int g = lane & 15;

    const int st = s_tab[b * T_ + n];
    const int s  = (st < 0) ? 0 : st;

    const unsigned short* kb = kp + (size_t)b * C_ * H_;
    const unsigned short* vb = vp + (size_t)b * C_ * H_;
    ushort4 qu = *(const ushort4*)&qp[((size_t)b * C_ + 4 * n + a) * H_ + 4 * g];
    f32x4 q4 = { bf2f(qu.x), bf2f(qu.y), bf2f(qu.z), bf2f(qu.w) };

    f32x4 acc = {};
#pragma unroll
    for (int ma = 0; ma < NA; ++ma) {
        const int m = 4 * n + ma;
        ushort4 ku = *(const ushort4*)&kb[(size_t)m * H_ + 4 * g];
        float p = q4[0] * bf2f(ku.x) + q4[1] * bf2f(ku.y)
                + q4[2] * bf2f(ku.z) + q4[3] * bf2f(ku.w);
        p += __shfl_xor(p, 1); p += __shfl_xor(p, 2);
        p += __shfl_xor(p, 4); p += __shfl_xor(p, 8);
        if (ma <= a) {
            ushort4 vu = *(const ushort4*)&vb[(size_t)m * H_ + 4 * g];
            acc[0] += p * bf2f(vu.x); acc[1] += p * bf2f(vu.y);
            acc[2] += p * bf2f(vu.z); acc[3] += p * bf2f(vu.w);
        }
    }
    float decay = KAPPA;
    for (int mt = n - 1; mt >= s; --mt) {
#pragma unroll
        for (int ma = 0; ma < NA; ++ma) {
            const int m = 4 * mt + ma;
            ushort4 ku = *(const ushort4*)&kb[(size_t)m * H_ + 4 * g];
            float p = q4[0] * bf2f(ku.x) + q4[1] * bf2f(ku.y)
                    + q4[2] * bf2f(ku.z) + q4[3] * bf2f(ku.w);
            p += __shfl_xor(p, 1); p += __shfl_xor(p, 2);
            p += __shfl_xor(p, 4); p += __shfl_xor(p, 8);
            p *= decay;
            ushort4 vu = *(const ushort4*)&vb[(size_t)m * H_ + 4 * g];
            acc[0] += p * bf2f(vu.x); acc[1] += p * bf2f(vu.y);
            acc[2] += p * bf2f(vu.z); acc[3] += p * bf2f(vu.w);
        }
        decay *= KAPPA;
    }
    if (st < 0) {
        const float xi = exp2f(LOG2_KAPPA * (float)(n + 1));
        const float* hsb = hs + (size_t)b * H_ * H_;
        f32x4 cacc = {};
#pragma unroll
        for (int h = 0; h < H_; ++h) {
            float qh = __shfl(q4[h & 3], (a << 4) + (h >> 2));
            f32x4 h4 = *(const f32x4*)&hsb[h * H_ + 4 * g];
            cacc[0] += qh * h4[0]; cacc[1] += qh * h4[1];
            cacc[2] += qh * h4[2]; cacc[3] += qh * h4[3];
        }
        acc[0] += xi * cacc[0]; acc[1] += xi * cacc[1];
        acc[2] += xi * cacc[2]; acc[3] += xi * cacc[3];
    }
    *(f32x4*)&out0[((size_t)b * C_ + 4 * n + a) * H_ + 4 * g] = acc;
}

__device__ inline void do_nexth_unit(
    int j, int t, const unsigned short* kp, const unsigned short* vp,
    const float* hs, const int* s_tab, float* outh)
{
    const int lane = t & 63;
    const int wv   = t >> 6;
    const int b = j & 7;
    const int h = (j >> 3) * 4 + wv;
    const int d = lane;

    const int st = s_tab[b * T_ + (T_ - 1)];
    const int s  = (st < 0) ? 0 : st;

    const unsigned short* kb = kp + (size_t)b * C_ * H_;
    const unsigned short* vb = vp + (size_t)b * C_ * H_;
    float acc = 0.f, wdec = 1.f;
    for (int mt = T_ - 1; mt >= s; --mt) {
#pragma unroll
        for (int ma = 0; ma < NA; ++ma) {
            const int m = 4 * mt + ma;
            acc += wdec * bf2f(kb[(size_t)m * H_ + h]) *
                          bf2f(vb[(size_t)m * H_ + d]);
        }
        wdec *= KAPPA;
    }
    if (st < 0)
        acc += hs[((size_t)b * H_ + h) * H_ + d] * KAPPA_T;
    outh[((size_t)b * H_ + h) * H_ + d] = acc;
}

// ========== Kernel 1: proj, 128-row blocks (2 m-tiles/wave) + s_tab =========
// GEMM blocks 0-383: mat = bid>>7, j = bid&127, b = j&7 (XCD pin),
// rows [b*2048 + (j>>3)*128, +128). Each wave owns 2 m-tiles of 16 rows and
// reuses each B-fragment ds_read for 2 MFMAs; W transpose done 384x not 768x.
// s_tab side-cars: blocks 384-391.
__global__ __launch_bounds__(256) void proj_mfma(
    const float* __restrict__ key_in, const float* __restrict__ query,
    const float* __restrict__ value,
    const float* __restrict__ w_q, const float* __restrict__ w_k,
    const float* __restrict__ w_v,
    const unsigned char* __restrict__ raw,
    unsigned short* __restrict__ qp, unsigned short* __restrict__ kp,
    unsigned short* __restrict__ vp, int* __restrict__ s_tab)
{
    __shared__ __align__(16) char Wt[64 * 512];   // 32KB swizzled bf16 image
    const int t   = threadIdx.x;
    const int bid = blockIdx.x;

    if (bid >= 384) { do_stab_block(bid - 384, t, raw, s_tab); return; }

    const int mat = bid >> 7;
    const int j   = bid & 127;
    const float* A; unsigned short* O16; const float* Wg;
    if (mat == 0)      { A = query;  O16 = qp; Wg = w_q; }
    else if (mat == 1) { A = key_in; O16 = kp; Wg = w_k; }
    else               { A = value;  O16 = vp; Wg = w_v; }

    const int b    = j & 7;
    const int rbig = j >> 3;                 // 0..15
    const int row0 = b * C_ + rbig * 128;
    const int lane = t & 63;
    const int wv   = t >> 6;
    const int lr   = lane & 15;
    const int lg   = lane >> 4;
    const int swz  = (lr & 7) << 4;

    // in-block W transpose: W[256][64] f32 -> swizzled bf16 Wt
#pragma unroll
    for (int p = 0; p < 8; ++p) {
        int idx = p * 256 + t;
        int kpair = idx >> 4;
        int dq    = (idx & 15) * 4;
        f32x4 r0 = *(const f32x4*)&Wg[(size_t)(2 * kpair)     * H_ + dq];
        f32x4 r1 = *(const f32x4*)&Wg[(size_t)(2 * kpair + 1) * H_ + dq];
#pragma unroll
        for (int jj = 0; jj < 4; ++jj) {
            int d = dq + jj;
            *(unsigned*)&Wt[(d << 9) + ((4 * kpair) ^ ((d & 7) << 4))] =
                cvtpk(r0[jj], r1[jj]);
        }
    }

    const float* arowA = &A[(size_t)(row0 + wv * 32 + lr) * E_ + lg * 8];
    const float* arowB = arowA + 16 * E_;    // second m-tile, +16 rows

    f32x4 xa0 = *(const f32x4*)(arowA);
    f32x4 xa1 = *(const f32x4*)(arowA + 4);
    f32x4 xb0 = *(const f32x4*)(arowB);
    f32x4 xb1 = *(const f32x4*)(arowB + 4);
    __syncthreads();

    f32x4 acc0[4] = {};
    f32x4 acc1[4] = {};
#pragma unroll
    for (int kc = 0; kc < 8; ++kc) {
        f32x4 na0, na1, nb0, nb1;
        if (kc < 7) {
            na0 = *(const f32x4*)(arowA + (kc + 1) * 32);
            na1 = *(const f32x4*)(arowA + (kc + 1) * 32 + 4);
            nb0 = *(const f32x4*)(arowB + (kc + 1) * 32);
            nb1 = *(const f32x4*)(arowB + (kc + 1) * 32 + 4);
        }
        u32x4 au = { cvtpk(xa0[0], xa0[1]), cvtpk(xa0[2], xa0[3]),
                     cvtpk(xa1[0], xa1[1]), cvtpk(xa1[2], xa1[3]) };
        u32x4 bu = { cvtpk(xb0[0], xb0[1]), cvtpk(xb0[2], xb0[3]),
                     cvtpk(xb1[0], xb1[1]), cvtpk(xb1[2], xb1[3]) };
        bf16x8 afA = __builtin_bit_cast(bf16x8, au);
        bf16x8 afB = __builtin_bit_cast(bf16x8, bu);
#pragma unroll
        for (int nt = 0; nt < 4; ++nt) {
            bf16x8 bfrag = *(const bf16x8*)&Wt[((nt * 16 + lr) << 9) +
                                               ((kc * 64 + lg * 16) ^ swz)];
            acc0[nt] = __builtin_amdgcn_mfma_f32_16x16x32_bf16(afA, bfrag, acc0[nt], 0, 0, 0);
            acc1[nt] = __builtin_amdgcn_mfma_f32_16x16x32_bf16(afB, bfrag, acc1[nt], 0, 0, 0);
        }
        xa0 = na0; xa1 = na1; xb0 = nb0; xb1 = nb1;
    }

    // packed bf16 epilogue for both m-tiles (dword stores via lane-pair shfl)
    const int odd = lr & 1;
#pragma unroll
    for (int mt2 = 0; mt2 < 2; ++mt2) {
        f32x4* acc = mt2 ? acc1 : acc0;
        const int rbase = row0 + wv * 32 + mt2 * 16 + lg * 4;
#pragma unroll
        for (int nt = 0; nt < 4; ++nt) {
            const int cp = nt * 16 + (lr & ~1);
            float x0_ = acc[nt][0], x1_ = acc[nt][1], x2_ = acc[nt][2], x3_ = acc[nt][3];
            float y0 = __shfl_xor(x0_, 1), y1 = __shfl_xor(x1_, 1);
            float y2 = __shfl_xor(x2_, 1), y3 = __shfl_xor(x3_, 1);
            if (!odd) {
                *(unsigned*)&O16[(size_t)(rbase + 0) * H_ + cp] = pack2bf(x0_, y0);
                *(unsigned*)&O16[(size_t)(rbase + 1) * H_ + cp] = pack2bf(x1_, y1);
            } else {
                *(unsigned*)&O16[(size_t)(rbase + 2) * H_ + cp] = pack2bf(y2, x2_);
                *(unsigned*)&O16[(size_t)(rbase + 3) * H_ + cp] = pack2bf(y3, x3_);
            }
        }
    }
}

// ============ Kernel 2: out0 (blocks 0-1023) + next_h (1024-1151) ===========
__global__ __launch_bounds__(256) void out_kernel(
    const unsigned short* __restrict__ qp, const unsigned short* __restrict__ kp,
    const unsigned short* __restrict__ vp, const float* __restrict__ hs,
    const int* __restrict__ s_tab,
    float* __restrict__ out0, float* __restrict__ outh)
{
    const int t   = threadIdx.x;
    const int bid = blockIdx.x;
    if (bid < 1024) do_out0_unit(bid, t, qp, kp, vp, hs, s_tab, out0);
    else            do_nexth_unit(bid - 1024, t, kp, vp, hs, s_tab, outh);
}

extern "C" void kernel_launch(void* const* d_in, const int* in_sizes, int n_in,
                              void* d_out, int out_size, void* d_ws, size_t ws_size,
                              hipStream_t stream)
{
    const float* key_in = (const float*)d_in[0];
    const float* query  = (const float*)d_in[1];
    const float* value  = (const float*)d_in[2];
    const float* hstate = (const float*)d_in[3];
    const unsigned char* dones = (const unsigned char*)d_in[4];
    const float* w_q = (const float*)d_in[5];
    const float* w_k = (const float*)d_in[6];
    const float* w_v = (const float*)d_in[7];

    unsigned short* qp = (unsigned short*)d_ws;
    unsigned short* kp = qp + (size_t)B_ * C_ * H_;
    unsigned short* vp = kp + (size_t)B_ * C_ * H_;
    int*         s_tab = (int*)(vp + (size_t)B_ * C_ * H_);

    proj_mfma<<<392, 256, 0, stream>>>(key_in, query, value,
                                       w_q, w_k, w_v, dones,
                                       qp, kp, vp, s_tab);
    out_kernel<<<1024 + 128, 256, 0, stream>>>(
        qp, kp, vp, hstate, s_tab,
        (float*)d_out, (float*)d_out + (size_t)B_ * C_ * H_);
}

// Round 22
// 26.195 us; speedup vs baseline: 1.1394x; 1.0259x over previous
//
#include <hip/hip_runtime.h>
#include <hip/hip_bf16.h>
#include <cstddef>

#define B_ 8
#define C_ 2048
#define E_ 256
#define H_ 64
#define T_ 512
#define NA 4
#define KAPPA 0.9f
#define LOG2_KAPPA (-0.15200309344504997f)   // log2(0.9)
#define KAPPA_T 3.73302e-24f                 // 0.9^512

typedef __attribute__((ext_vector_type(8))) short bf16x8;
typedef __attribute__((ext_vector_type(4))) float f32x4;
typedef __attribute__((ext_vector_type(4))) unsigned u32x4;

__device__ inline unsigned short f2bfu(float x) {
    unsigned u = __builtin_bit_cast(unsigned, x);
    u += 0x7fff + ((u >> 16) & 1);   // RNE
    return (unsigned short)(u >> 16);
}
__device__ inline float bf2f(unsigned short u) {
    return __builtin_bit_cast(float, (unsigned)u << 16);
}
__device__ inline unsigned pack2bf(float lo, float hi) {
    return (unsigned)f2bfu(lo) | ((unsigned)f2bfu(hi) << 16);
}
// packed RNE cvt: lowers to v_cvt_pk_bf16_f32 (1 VALU op / 2 elems).
__device__ inline unsigned cvtpk(float a, float b) {
    __hip_bfloat162 h = __float22bfloat162_rn(float2{a, b});
    unsigned r;
    __builtin_memcpy(&r, &h, sizeof(r));
    return r;
}

// ========== Kernel 1: proj 128-row/512-thread blocks + s_tab side-cars ======
// GEMM blocks 0-383: mat = bid/128, j = bid%128, b = j&7 (XCD pin),
// rows [b*2048 + (j>>3)*128, +128). Two 4-wave groups each own a 64-row
// sub-slab with r18's exact per-wave shape; ONE shared W transpose per block
// (half the transposes of r18, same 3072 total waves, 32 waves/CU occupancy).
// s_tab side-cars: blocks 384-391 (512 threads, one 64-chunk per wave).
__global__ __launch_bounds__(512) void proj_mfma(
    const float* __restrict__ key_in, const float* __restrict__ query,
    const float* __restrict__ value,
    const float* __restrict__ w_q, const float* __restrict__ w_k,
    const float* __restrict__ w_v,
    const unsigned char* __restrict__ raw,
    unsigned short* __restrict__ qp, unsigned short* __restrict__ kp,
    unsigned short* __restrict__ vp, int* __restrict__ s_tab)
{
    __shared__ __align__(16) char Wt[64 * 512];   // 32KB swizzled bf16 image
    const int t   = threadIdx.x;
    const int bid = blockIdx.x;

    if (bid >= 384) {
        // ---- s_tab for batch b: last done timestep <= n, or -1 ----
        const int b    = bid - 384;
        const int lane = t & 63;
        const int wv   = t >> 6;               // 0..7 = chunk id
        __shared__ int f;
        __shared__ unsigned long long msk[8];
        if (t == 0) f = 0;
        __syncthreads();
        {   // layout detection: bool(1B) vs int32(4B LE 0/1)
            const uint4* dp = (const uint4*)raw;
            unsigned acc = 0;
#pragma unroll
            for (int i = 0; i < 2; ++i) {
                uint4 v = dp[t + 512 * i];     // 16KB = B_*C_ bytes
                acc |= (v.x | v.y | v.z | v.w) & 0xFFFFFF00u;
            }
            if (acc) f = 1;
        }
        __syncthreads();
        const int stride = f ? 1 : 4;
        const unsigned char* drow = raw + (size_t)b * C_ * stride;
        {
            const int n = wv * 64 + lane;
            unsigned long long m = __ballot(drow[(size_t)(4 * n) * stride] != 0);
            if (lane == 0) msk[wv] = m;
        }
        __syncthreads();
        {
            const int c = wv;
            const int n = c * 64 + lane;
            unsigned long long lowmask =
                (lane == 63) ? ~0ULL : ((1ULL << (lane + 1)) - 1ULL);
            unsigned long long m_le = msk[c] & lowmask;
            int s = -1;
            if (m_le) {
                s = c * 64 + (63 - __builtin_clzll(m_le));
            } else {
                for (int c2 = c - 1; c2 >= 0; --c2)
                    if (msk[c2]) { s = c2 * 64 + (63 - __builtin_clzll(msk[c2])); break; }
            }
            s_tab[b * T_ + n] = s;
        }
        return;
    }

    const int mat = bid >> 7;
    const int j   = bid & 127;
    const float* A; unsigned short* O16; const float* Wg;
    if (mat == 0)      { A = query;  O16 = qp; Wg = w_q; }
    else if (mat == 1) { A = key_in; O16 = kp; Wg = w_k; }
    else               { A = value;  O16 = vp; Wg = w_v; }

    const int b    = j & 7;
    const int rbig = j >> 3;                 // 0..15
    const int row0 = b * C_ + rbig * 128;
    const int lane = t & 63;
    const int wg   = t >> 8;                 // 0/1: 64-row sub-slab
    const int mt   = (t >> 6) & 3;           // wave within group
    const int lr   = lane & 15;
    const int lg   = lane >> 4;
    const int swz  = (lr & 7) << 4;

    // in-block W transpose: W[256][64] f32 -> swizzled bf16 Wt (512 threads,
    // 4 passes x 4 dword-writes)
#pragma unroll
    for (int p = 0; p < 4; ++p) {
        int idx = p * 512 + t;
        int kpair = idx >> 4;
        int dq    = (idx & 15) * 4;
        f32x4 r0 = *(const f32x4*)&Wg[(size_t)(2 * kpair)     * H_ + dq];
        f32x4 r1 = *(const f32x4*)&Wg[(size_t)(2 * kpair + 1) * H_ + dq];
#pragma unroll
        for (int jj = 0; jj < 4; ++jj) {
            int d = dq + jj;
            *(unsigned*)&Wt[(d << 9) + ((4 * kpair) ^ ((d & 7) << 4))] =
                cvtpk(r0[jj], r1[jj]);
        }
    }

    const float* arow = &A[(size_t)(row0 + wg * 64 + mt * 16 + lr) * E_ + lg * 8];

    // prefetch kc=0 A while the transpose drains at the barrier
    f32x4 x0 = *(const f32x4*)(arow);
    f32x4 x1 = *(const f32x4*)(arow + 4);
    __syncthreads();

    f32x4 acc[4] = {};
#pragma unroll
    for (int kc = 0; kc < 8; ++kc) {
        f32x4 n0, n1;
        if (kc < 7) {
            n0 = *(const f32x4*)(arow + (kc + 1) * 32);
            n1 = *(const f32x4*)(arow + (kc + 1) * 32 + 4);
        }
        u32x4 afu = { cvtpk(x0[0], x0[1]), cvtpk(x0[2], x0[3]),
                      cvtpk(x1[0], x1[1]), cvtpk(x1[2], x1[3]) };
        bf16x8 af = __builtin_bit_cast(bf16x8, afu);
#pragma unroll
        for (int nt = 0; nt < 4; ++nt) {
            bf16x8 bfrag = *(const bf16x8*)&Wt[((nt * 16 + lr) << 9) +
                                               ((kc * 64 + lg * 16) ^ swz)];
            acc[nt] = __builtin_amdgcn_mfma_f32_16x16x32_bf16(af, bfrag, acc[nt], 0, 0, 0);
        }
        x0 = n0; x1 = n1;
    }

    // packed bf16 epilogue (dword stores via lane-pair shfl)
    const int odd   = lr & 1;
    const int rbase = row0 + wg * 64 + mt * 16 + lg * 4;
#pragma unroll
    for (int nt = 0; nt < 4; ++nt) {
        const int cp = nt * 16 + (lr & ~1);
        float x0_ = acc[nt][0], x1_ = acc[nt][1], x2_ = acc[nt][2], x3_ = acc[nt][3];
        float y0 = __shfl_xor(x0_, 1), y1 = __shfl_xor(x1_, 1);
        float y2 = __shfl_xor(x2_, 1), y3 = __shfl_xor(x3_, 1);
        if (!odd) {
            *(unsigned*)&O16[(size_t)(rbase + 0) * H_ + cp] = pack2bf(x0_, y0);
            *(unsigned*)&O16[(size_t)(rbase + 1) * H_ + cp] = pack2bf(x1_, y1);
        } else {
            *(unsigned*)&O16[(size_t)(rbase + 2) * H_ + cp] = pack2bf(y2, x2_);
            *(unsigned*)&O16[(size_t)(rbase + 3) * H_ + cp] = pack2bf(y3, x3_);
        }
    }
}

// ============ Kernel 2: out0 (blocks 0-1023) + next_h (1024-1151) ===========
__global__ __launch_bounds__(256) void out_kernel(
    const unsigned short* __restrict__ qp, const unsigned short* __restrict__ kp,
    const unsigned short* __restrict__ vp, const float* __restrict__ hs,
    const int* __restrict__ s_tab,
    float* __restrict__ out0, float* __restrict__ outh)
{
    const int t    = threadIdx.x;
    const int lane = t & 63;
    const int wv   = t >> 6;
    const int bid  = blockIdx.x;

    if (bid < 1024) {
        const int b = bid & 7;
        const int n = (bid >> 3) * 4 + wv;
        const int a = lane >> 4;
        const int g = lane & 15;

        const int st = s_tab[b * T_ + n];
        const int s  = (st < 0) ? 0 : st;

        const unsigned short* kb = kp + (size_t)b * C_ * H_;
        const unsigned short* vb = vp + (size_t)b * C_ * H_;
        ushort4 qu = *(const ushort4*)&qp[((size_t)b * C_ + 4 * n + a) * H_ + 4 * g];
        f32x4 q4 = { bf2f(qu.x), bf2f(qu.y), bf2f(qu.z), bf2f(qu.w) };

        f32x4 acc = {};
#pragma unroll
        for (int ma = 0; ma < NA; ++ma) {
            const int m = 4 * n + ma;
            ushort4 ku = *(const ushort4*)&kb[(size_t)m * H_ + 4 * g];
            float p = q4[0] * bf2f(ku.x) + q4[1] * bf2f(ku.y)
                    + q4[2] * bf2f(ku.z) + q4[3] * bf2f(ku.w);
            p += __shfl_xor(p, 1); p += __shfl_xor(p, 2);
            p += __shfl_xor(p, 4); p += __shfl_xor(p, 8);
            if (ma <= a) {
                ushort4 vu = *(const ushort4*)&vb[(size_t)m * H_ + 4 * g];
                acc[0] += p * bf2f(vu.x); acc[1] += p * bf2f(vu.y);
                acc[2] += p * bf2f(vu.z); acc[3] += p * bf2f(vu.w);
            }
        }
        float decay = KAPPA;
        for (int mt = n - 1; mt >= s; --mt) {
#pragma unroll
            for (int ma = 0; ma < NA; ++ma) {
                const int m = 4 * mt + ma;
                ushort4 ku = *(const ushort4*)&kb[(size_t)m * H_ + 4 * g];
                float p = q4[0] * bf2f(ku.x) + q4[1] * bf2f(ku.y)
                        + q4[2] * bf2f(ku.z) + q4[3] * bf2f(ku.w);
                p += __shfl_xor(p, 1); p += __shfl_xor(p, 2);
                p += __shfl_xor(p, 4); p += __shfl_xor(p, 8);
                p *= decay;
                ushort4 vu = *(const ushort4*)&vb[(size_t)m * H_ + 4 * g];
                acc[0] += p * bf2f(vu.x); acc[1] += p * bf2f(vu.y);
                acc[2] += p * bf2f(vu.z); acc[3] += p * bf2f(vu.w);
            }
            decay *= KAPPA;
        }
        if (st < 0) {
            const float xi = exp2f(LOG2_KAPPA * (float)(n + 1));
            const float* hsb = hs + (size_t)b * H_ * H_;
            f32x4 cacc = {};
#pragma unroll
            for (int h = 0; h < H_; ++h) {
                float qh = __shfl(q4[h & 3], (a << 4) + (h >> 2));
                f32x4 h4 = *(const f32x4*)&hsb[h * H_ + 4 * g];
                cacc[0] += qh * h4[0]; cacc[1] += qh * h4[1];
                cacc[2] += qh * h4[2]; cacc[3] += qh * h4[3];
            }
            acc[0] += xi * cacc[0]; acc[1] += xi * cacc[1];
            acc[2] += xi * cacc[2]; acc[3] += xi * cacc[3];
        }
        *(f32x4*)&out0[((size_t)b * C_ + 4 * n + a) * H_ + 4 * g] = acc;
    } else {
        const int j = bid - 1024;            // [0,128)
        const int b = j & 7;
        const int h = (j >> 3) * 4 + wv;     // [0,64)
        const int d = lane;

        const int st = s_tab[b * T_ + (T_ - 1)];
        const int s  = (st < 0) ? 0 : st;

        const unsigned short* kb = kp + (size_t)b * C_ * H_;
        const unsigned short* vb = vp + (size_t)b * C_ * H_;
        float acc = 0.f, wdec = 1.f;
        for (int mt = T_ - 1; mt >= s; --mt) {
#pragma unroll
            for (int ma = 0; ma < NA; ++ma) {
                const int m = 4 * mt + ma;
                acc += wdec * bf2f(kb[(size_t)m * H_ + h]) *
                              bf2f(vb[(size_t)m * H_ + d]);
            }
            wdec *= KAPPA;
        }
        if (st < 0)
            acc += hs[((size_t)b * H_ + h) * H_ + d] * KAPPA_T;
        outh[((size_t)b * H_ + h) * H_ + d] = acc;
    }
}

extern "C" void kernel_launch(void* const* d_in, const int* in_sizes, int n_in,
                              void* d_out, int out_size, void* d_ws, size_t ws_size,
                              hipStream_t stream)
{
    const float* key_in = (const float*)d_in[0];
    const float* query  = (const float*)d_in[1];
    const float* value  = (const float*)d_in[2];
    const float* hstate = (const float*)d_in[3];
    const unsigned char* dones = (const unsigned char*)d_in[4];
    const float* w_q = (const float*)d_in[5];
    const float* w_k = (const float*)d_in[6];
    const float* w_v = (const float*)d_in[7];

    unsigned short* qp = (unsigned short*)d_ws;
    unsigned short* kp = qp + (size_t)B_ * C_ * H_;
    unsigned short* vp = kp + (size_t)B_ * C_ * H_;
    int*         s_tab = (int*)(vp + (size_t)B_ * C_ * H_);

    proj_mfma<<<392, 512, 0, stream>>>(key_in, query, value,
                                       w_q, w_k, w_v, dones,
                                       qp, kp, vp, s_tab);
    out_kernel<<<1024 + 128, 256, 0, stream>>>(
        qp, kp, vp, hstate, s_tab,
        (float*)d_out, (float*)d_out + (size_t)B_ * C_ * H_);
}